// Round 6
// baseline (285.253 us; speedup 1.0000x reference)
//
#include <hip/hip_runtime.h>
#include <hip/hip_bf16.h>
#include <math.h>

#define NB 512
#define NPC 32
#define KNN 12
#define NL 4
#define NN (NB*NPC)
#define WPL 28672   // prepacked bf16 weight elems per layer
#define TSTR 72     // m2 tile row stride (shorts) — 144B rows: 16B-aligned b128 reads

typedef float v4f __attribute__((ext_vector_type(4)));
typedef float v2f __attribute__((ext_vector_type(2)));
typedef short s8v __attribute__((ext_vector_type(8)));   // 16 B = 4 VGPRs

__device__ __forceinline__ float silu_f(float x) {
    return x * __builtin_amdgcn_rcpf(1.0f + __builtin_amdgcn_exp2f(x * -1.44269504088896341f));
}

__device__ __forceinline__ v2f silu2(v2f x) {
    v2f n = x * -1.44269504088896341f;
    v2f e; e.x = __builtin_amdgcn_exp2f(n.x); e.y = __builtin_amdgcn_exp2f(n.y);
    v2f d = e + 1.0f;
    v2f r; r.x = __builtin_amdgcn_rcpf(d.x); r.y = __builtin_amdgcn_rcpf(d.y);
    return x * r;
}

__device__ __forceinline__ unsigned short f2bf(float x) {
    unsigned u = __float_as_uint(x);
    u += 0x7fffu + ((u >> 16) & 1u);
    return (unsigned short)(u >> 16);
}

__device__ __forceinline__ unsigned pk2bf(float a, float b) {
    __hip_bfloat162 t = __float22bfloat162_rn(make_float2(a, b));
    union { __hip_bfloat162 h; unsigned u; } c; c.h = t;
    return c.u;
}
__device__ __forceinline__ unsigned pk2bfu(v2f s) { return pk2bf(s.x, s.y); }

template<int R>
__device__ __forceinline__ void gemm_acc(const float* A, int astride,
                                         const float* __restrict__ Wg,
                                         int K, int lane, float* acc) {
#pragma unroll 2
    for (int kq = 0; kq < (K >> 2); ++kq) {
        float w0 = Wg[(4*kq+0)*64 + lane];
        float w1 = Wg[(4*kq+1)*64 + lane];
        float w2 = Wg[(4*kq+2)*64 + lane];
        float w3 = Wg[(4*kq+3)*64 + lane];
#pragma unroll
        for (int r = 0; r < R; ++r) {
            float4 a = *(const float4*)(A + r*astride + 4*kq);
            acc[r] = fmaf(a.x, w0, acc[r]);
            acc[r] = fmaf(a.y, w1, acc[r]);
            acc[r] = fmaf(a.z, w2, acc[r]);
            acc[r] = fmaf(a.w, w3, acc[r]);
        }
    }
}

// ---------------- prepack (unchanged) ----------------
extern "C" __global__ void prepack_w(const float* __restrict__ edge_w1, const float* __restrict__ edge_w2,
                                     const float* __restrict__ coord_w1, const float* __restrict__ node_w1,
                                     const float* __restrict__ node_w2, unsigned short* __restrict__ wout) {
    int g = blockIdx.x * 256 + threadIdx.x;
    if (g >= 4 * WPL / 8) return;
    int l = (g * 8) / WPL;
    int r = (g * 8) % WPL;
    int base, nKt, mat;
    if      (r < 8192)  { base = 0;     nKt = 2; mat = 0; }
    else if (r < 12288) { base = 8192;  nKt = 2; mat = 1; }
    else if (r < 16384) { base = 12288; nKt = 2; mat = 2; }
    else if (r < 24576) { base = 16384; nKt = 4; mat = 3; }
    else                { base = 24576; nKt = 2; mat = 4; }
    int idx = r - base;
    int lane = (idx >> 3) & 63, t = idx >> 9;
    int kt = t % nKt, nt = t / nKt;
    int k0 = kt*32 + ((lane >> 4) & 3)*8;
    int n  = nt*16 + (lane & 15);
    unsigned short o[8];
#pragma unroll
    for (int j = 0; j < 8; ++j) {
        int k = k0 + j;
        float v;
        if      (mat == 0) v = (n < 64) ? edge_w1[l*193*64 + k*64 + n] : edge_w1[l*193*64 + (64+k)*64 + (n-64)];
        else if (mat == 1) v = edge_w2 [l*4096 + k*64 + n];
        else if (mat == 2) v = coord_w1[l*4096 + k*64 + n];
        else if (mat == 3) v = node_w1 [l*192*64 + k*64 + n];
        else               v = node_w2 [l*4096 + k*64 + n];
        o[j] = f2bf(v);
    }
    *(s8v*)(wout + g*8) = *(s8v*)o;
}

// ---------------- main fused kernel: one block (16 waves) per crystal ----------------
// R19: 16 waves/crystal (1024 threads) -> 2 blocks x 16 = 32 waves/CU, the
// VGPR=64 hardware cap (8 waves/SIMD). Established laws: grid=512 caps
// blocks/CU at 2 (work-limited); reported VGPR must be <=64 for >2 waves/SIMD
// (R18: 64->16 waves/CU; R16/17: 92->8); proven-schedulable LDS: 2x73728.
// Work split 16 ways:
//  - edge phase: tile = 12 edges = ONE dst (2 tiles/wave). Kills thr/slot/
//    div12 logic; hd row is wave-uniform (broadcast read). MFMA rows 12-15
//    are clamped duplicates, masked at msum (q4==3) and at the shift atomic.
//  - step A: 16 tasks (mt split).  - node GEMMs: 8 tasks, waves 8-15 idle
//    through the short B3->B5 window.
//  - w2/wc1 B-frags from GLOBAL at use (L1/L2-hot, 16KB/layer) — frees the
//    16KB LDS stage so the 16-wave tile region fits: total 72648 <= 73728.
//  - prologue smalls (sinu/t1/tf/frac) aliased into the tile scratch.
extern "C" __global__ __launch_bounds__(1024, 2)
void crystal_fused(const float* __restrict__ z_nodes, const float* __restrict__ t_in,
                   const float* __restrict__ frac,    const float* __restrict__ lattice,
                   const float* __restrict__ time_w1, const float* __restrict__ time_b1,
                   const float* __restrict__ time_w2, const float* __restrict__ time_b2,
                   const float* __restrict__ emb_w,   const float* __restrict__ emb_b,
                   const float* __restrict__ edge_w1, const float* __restrict__ edge_b1,
                   const float* __restrict__ edge_b2, const float* __restrict__ coord_b1,
                   const float* __restrict__ coord_w2,
                   const float* __restrict__ node_w1, const float* __restrict__ node_b1,
                   const float* __restrict__ node_b2,
                   const unsigned short* __restrict__ wbf,
                   float* __restrict__ out)
{
    __shared__ __align__(16) unsigned short s_tiles16[16*16*TSTR]; // 36864 B multi-use scratch
    __shared__ __align__(16) unsigned short s_habf[32*136];        // bf16 [h | m_i]  8704
    __shared__ __align__(16) float s_hs[32*68];                    // 8704
    __shared__ __align__(16) float s_hd[32*68];                    // 8704
    __shared__ __align__(16) float s_endc[384*3];                  // 4608
    __shared__ float s_edsq[384];                                  // 1536
    __shared__ unsigned short s_esrc[384];                         // 768
    __shared__ float s_shift[96];                                  // 384 (frac alias in prologue)
    __shared__ float s_lat[9], s_inv[9];                           // 72
    __shared__ float s_tb4[NL*64], s_nb4[NL*64];                   // 2048
    __shared__ float s_w1r[64];                                    // 256

    // scratch aliases inside s_tiles16 (lifetimes disjoint, barrier-separated):
    float* dcf = (float*)s_tiles16;                                 // [1024][3] 12288, ph1-2
    float (*s_dsq)[33] = (float(*)[33])((char*)s_tiles16 + 12288);  // 4224, ph1-2
    float* s_sinu = (float*)((char*)s_tiles16 + 16512);             // 256, ph0-2
    float* s_t1   = (float*)((char*)s_tiles16 + 16768);             // 512, ph2-3
    float* s_tf   = (float*)((char*)s_tiles16 + 17280);             // 256, ph3-4
    float* s_hf   = (float*)s_tiles16;                              // 8192, ph4 only
    unsigned short* s_n1bf = s_tiles16;                             // 4608, B3->B5
    float (*s_frac)[3] = (float(*)[3])s_shift;                      // 384, ph0-1 (shift zeroed ph3)

    const int tid  = threadIdx.x;
    const int c    = blockIdx.x;
    const int lane = tid & 63;
    const int wave = tid >> 6;       // 0..15
    const int q4   = lane >> 4;
    const int c16  = lane & 15;
    const int base = c * NPC;

    // ---------------- phase 0 ----------------
    if (tid < 96) {
        ((float*)s_frac)[tid] = frac[base*3 + tid];
    } else if (tid < 105) {
        s_lat[tid-96] = lattice[c*9 + (tid-96)];
    } else if (tid >= 128 && tid < 160) {
        int i = tid - 128;
        float freq = expf((float)i * (-9.210340371976184f / 31.0f));
        float ang  = t_in[c] * freq;
        s_sinu[i]    = sinf(ang);
        s_sinu[i+32] = cosf(ang);
    }
    __syncthreads();

    // ---------------- phase 1: PBC pair distances (1024 threads = 1 shot) ----------------
    {
        float l00=s_lat[0],l01=s_lat[1],l02=s_lat[2];
        float l10=s_lat[3],l11=s_lat[4],l12=s_lat[5];
        float l20=s_lat[6],l21=s_lat[7],l22=s_lat[8];
        int p = tid;
        int i = p >> 5, j = p & 31;
        float dx = s_frac[i][0]-s_frac[j][0];
        float dy = s_frac[i][1]-s_frac[j][1];
        float dz = s_frac[i][2]-s_frac[j][2];
        dx -= rintf(dx); dy -= rintf(dy); dz -= rintf(dz);
        float cx = dx*l00 + dy*l10 + dz*l20;
        float cy = dx*l01 + dy*l11 + dz*l21;
        float cz = dx*l02 + dy*l12 + dz*l22;
        float dd = cx*cx + cy*cy + cz*cz;
        s_dsq[i][j] = (i==j) ? 3.0e38f : dd;
        dcf[p*3+0]=cx; dcf[p*3+1]=cy; dcf[p*3+2]=cz;
    }
    __syncthreads();

    // ---------------- phase 2: parallel KNN (8 lanes/row) || time-MLP L1 ----------------
    if (tid < 256) {
        int i = tid >> 3, g = tid & 7;
        float d0 = s_dsq[i][g*4+0];
        float d1 = s_dsq[i][g*4+1];
        float d2 = s_dsq[i][g*4+2];
        float d3 = s_dsq[i][g*4+3];
        for (int k = 0; k < KNN; ++k) {
            float v = d0; int jl = g*4;
            if (d1 < v) { v = d1; jl = g*4+1; }
            if (d2 < v) { v = d2; jl = g*4+2; }
            if (d3 < v) { v = d3; jl = g*4+3; }
            float ov; int oj;
            ov = __shfl_xor(v, 1); oj = __shfl_xor(jl, 1);
            if (ov < v || (ov == v && oj < jl)) { v = ov; jl = oj; }
            ov = __shfl_xor(v, 2); oj = __shfl_xor(jl, 2);
            if (ov < v || (ov == v && oj < jl)) { v = ov; jl = oj; }
            ov = __shfl_xor(v, 4); oj = __shfl_xor(jl, 4);
            if (ov < v || (ov == v && oj < jl)) { v = ov; jl = oj; }
            if ((jl >> 2) == g) {
                int s = jl & 3;
                if      (s == 0) d0 = 3.9e38f;
                else if (s == 1) d1 = 3.9e38f;
                else if (s == 2) d2 = 3.9e38f;
                else             d3 = 3.9e38f;
            }
            if (g == 0) {
                int e = i*KNN + k;
                s_edsq[e] = v;
                s_esrc[e] = (unsigned short)jl;
                int p = (i<<5) + jl;
                s_endc[e*3+0] = dcf[p*3+0];
                s_endc[e*3+1] = dcf[p*3+1];
                s_endc[e*3+2] = dcf[p*3+2];
            }
        }
    } else if (tid < 384) {
        int jj = tid - 256;
        float p0 = time_b1[jj], p1=0.f, p2=0.f, p3=0.f;
        for (int k = 0; k < 64; k += 4) {
            p0 = fmaf(s_sinu[k+0], time_w1[(k+0)*128+jj], p0);
            p1 = fmaf(s_sinu[k+1], time_w1[(k+1)*128+jj], p1);
            p2 = fmaf(s_sinu[k+2], time_w1[(k+2)*128+jj], p2);
            p3 = fmaf(s_sinu[k+3], time_w1[(k+3)*128+jj], p3);
        }
        s_t1[jj] = silu_f((p0+p1) + (p2+p3));
    }
    __syncthreads();

    // ---------------- phase 3: t_feat ; zero shift ----------------
    if (tid < 64) {
        float p0=time_b2[tid],p1=0.f,p2=0.f,p3=0.f;
        for (int k = 0; k < 128; k += 4) {
            p0 = fmaf(s_t1[k+0], time_w2[(k+0)*64+tid], p0);
            p1 = fmaf(s_t1[k+1], time_w2[(k+1)*64+tid], p1);
            p2 = fmaf(s_t1[k+2], time_w2[(k+2)*64+tid], p2);
            p3 = fmaf(s_t1[k+3], time_w2[(k+3)*64+tid], p3);
        }
        s_tf[tid] = (p0+p1) + (p2+p3);
    } else if (tid < 160) {
        s_shift[tid-64] = 0.0f;
    }
    __syncthreads();

    // ---------------- phase 4: t-term GEMVs (waves 0-7) + embedding (2 rows/wave) ----------------
    if (wave < 8) {
        int lt = wave >> 1, kind = wave & 1;
        const float* Wt = kind ? (node_w1 + lt*192*64 + 128*64) : (edge_w1 + lt*193*64 + 129*64);
        const float* bb = kind ? (node_b1 + lt*64) : (edge_b1 + lt*64);
        float p0 = bb[lane], p1=0.f, p2=0.f, p3=0.f;
        for (int k = 0; k < 64; k += 4) {
            p0 = fmaf(s_tf[k+0], Wt[(k+0)*64 + lane], p0);
            p1 = fmaf(s_tf[k+1], Wt[(k+1)*64 + lane], p1);
            p2 = fmaf(s_tf[k+2], Wt[(k+2)*64 + lane], p2);
            p3 = fmaf(s_tf[k+3], Wt[(k+3)*64 + lane], p3);
        }
        float v = (p0+p1) + (p2+p3);
        if (kind) s_nb4[lt*64 + lane] = v;
        else      s_tb4[lt*64 + lane] = v;
    }
    {
        float acc[2];
#pragma unroll
        for (int r = 0; r < 2; ++r) acc[r] = emb_b[lane];
        gemm_acc<2>(z_nodes + (base + wave*2)*128, 128, emb_w, 128, lane, acc);
#pragma unroll
        for (int r = 0; r < 2; ++r) {
            int row = wave*2 + r;
            s_hf[row*64 + lane] = acc[r];
            s_habf[row*136 + lane] = f2bf(acc[r]);
        }
    }
    __syncthreads();    // habf + hf ready

    // waves 0-7 own the h C-tiles in registers across all layers
    const int mtA = wave & 1, ntA = wave >> 1;   // meaningful for wave<8
    float h_reg[4] = {0.f, 0.f, 0.f, 0.f};
    if (wave < 8) {
        int colh = ntA*16 + c16;
#pragma unroll
        for (int r = 0; r < 4; ++r)
            h_reg[r] = s_hf[(mtA*16 + q4*4 + r)*64 + colh];
    }

    // ---------------- EGNN layers ----------------
    for (int l = 0; l < NL; ++l) {
        const unsigned short* wl = wbf + l*WPL;

        if (tid < 64) s_w1r[tid] = edge_w1[l*193*64 + 128*64 + tid];

        float b2e_v[4], cb1_v[4], w2c_v[4];
#pragma unroll
        for (int nt = 0; nt < 4; ++nt) {
            b2e_v[nt] = edge_b2 [l*64 + nt*16 + c16];
            cb1_v[nt] = coord_b1[l*64 + nt*16 + c16];
            w2c_v[nt] = coord_w2[l*64 + nt*16 + c16];
        }

        // ---- step A: 16 tasks — sd = wave>>3 (0:hs 1:hd), wn = wave&3, mt = (wave>>2)&1 ----
        {
            const int wn = wave & 3;
            const int mt = (wave >> 2) & 1;
            const int sd = wave >> 3;
            s8v a[2];
#pragma unroll
            for (int kt = 0; kt < 2; ++kt)
                a[kt] = *(const s8v*)(s_habf + (mt*16 + c16)*136 + kt*32 + q4*8);
            v4f acc = {0.f,0.f,0.f,0.f};
#pragma unroll
            for (int kt = 0; kt < 2; ++kt) {
                s8v b = *(const s8v*)(wl + (((wn + sd*4)*2 + kt)*64 + lane)*8);
                acc = __builtin_amdgcn_mfma_f32_16x16x32_bf16(a[kt], b, acc, 0, 0, 0);
            }
            int col = wn*16 + c16;
            if (sd) {
                float tbv = s_tb4[l*64 + col];
#pragma unroll
                for (int reg = 0; reg < 4; ++reg)
                    s_hd[(mt*16 + q4*4 + reg)*68 + col] = acc[reg] + tbv;
            } else {
#pragma unroll
                for (int reg = 0; reg < 4; ++reg)
                    s_hs[(mt*16 + q4*4 + reg)*68 + col] = acc[reg];
            }
        }
        __syncthreads();    // B2

        // ---- edge phase: wave owns dsts {2*wave, 2*wave+1}; tile = 12 edges = 1 dst ----
        {
            unsigned short* tile = s_tiles16 + wave*16*TSTR;
#pragma unroll 1
            for (int t = 0; t < 2; ++t) {
                const int d  = wave*2 + t;
                const int e0 = d*KNN;
                const int cc = (c16 < 12) ? c16 : 11;      // clamp: rows 12-15 duplicate edge 11
                const float dq = s_edsq[e0 + cc];
                const int  srcn = s_esrc[e0 + cc];
                const float* hsr = s_hs + srcn*68;
                const float* hdr = s_hd + d*68;            // uniform row: broadcast
                // fused A-build
                union S8 { s8v v; unsigned u[4]; } A0, A1;
#pragma unroll
                for (int g2 = 0; g2 < 4; ++g2) {
                    int off = ((g2 & 2) ? 32 : 0) + ((g2 & 1) ? 4 : 0) + q4*8;
                    float4 Hv = *(const float4*)(hsr + off);
                    float4 Gv = *(const float4*)(hdr + off);
                    float4 Wv = *(const float4*)(s_w1r + off);
                    v2f t0 = {Hv.x + Gv.x + Wv.x*dq, Hv.y + Gv.y + Wv.y*dq};
                    v2f t1 = {Hv.z + Gv.z + Wv.z*dq, Hv.w + Gv.w + Wv.w*dq};
                    unsigned lo  = pk2bfu(silu2(t0));
                    unsigned hi2 = pk2bfu(silu2(t1));
                    if (g2 < 2) { A0.u[g2*2] = lo; A0.u[g2*2+1] = hi2; }
                    else        { A1.u[(g2-2)*2] = lo; A1.u[(g2-2)*2+1] = hi2; }
                }

                // m2 = silu(m1@W2 + b2); W2 B-frags from GLOBAL (L1/L2-hot)
                float miacc[4] = {0.f, 0.f, 0.f, 0.f};
#pragma unroll
                for (int nt = 0; nt < 4; ++nt) {
                    s8v b0 = *(const s8v*)(wl +  8192 + ((nt*2+0)*64 + lane)*8);
                    s8v b1 = *(const s8v*)(wl +  8192 + ((nt*2+1)*64 + lane)*8);
                    v4f acc = {0.f,0.f,0.f,0.f};
                    acc = __builtin_amdgcn_mfma_f32_16x16x32_bf16(A0.v, b0, acc, 0,0,0);
                    acc = __builtin_amdgcn_mfma_f32_16x16x32_bf16(A1.v, b1, acc, 0,0,0);
                    int col = nt*16 + c16;
                    v2f z01 = {acc[0] + b2e_v[nt], acc[1] + b2e_v[nt]};
                    v2f z23 = {acc[2] + b2e_v[nt], acc[3] + b2e_v[nt]};
                    v2f s01 = silu2(z01), s23 = silu2(z23);
                    unsigned p01 = pk2bfu(s01), p23 = pk2bfu(s23);
                    tile[(q4*4 + 0)*TSTR + col] = (unsigned short)p01;
                    tile[(q4*4 + 1)*TSTR + col] = (unsigned short)(p01 >> 16);
                    tile[(q4*4 + 2)*TSTR + col] = (unsigned short)p23;
                    tile[(q4*4 + 3)*TSTR + col] = (unsigned short)(p23 >> 16);
                    // rows 12-15 (q4==3) are duplicates: exclude from m_i
                    float msum = (q4 == 3) ? 0.f : ((s01.x + s01.y) + (s23.x + s23.y));
                    miacc[nt] += msum;
                }
                asm volatile("s_waitcnt lgkmcnt(0)" ::: "memory");
                s8v c0 = *(const s8v*)(tile + c16*TSTR +      q4*8);
                s8v c1 = *(const s8v*)(tile + c16*TSTR + 32 + q4*8);
                // cw = silu(m2@Wc1 + cb1) . w2c ; Wc1 B-frags from GLOBAL
                v2f cwp01 = {0.f, 0.f}, cwp23 = {0.f, 0.f};
#pragma unroll
                for (int nt = 0; nt < 4; ++nt) {
                    s8v wb0 = *(const s8v*)(wl + 12288 + ((nt*2+0)*64 + lane)*8);
                    s8v wb1 = *(const s8v*)(wl + 12288 + ((nt*2+1)*64 + lane)*8);
                    v4f acc = {0.f,0.f,0.f,0.f};
                    acc = __builtin_amdgcn_mfma_f32_16x16x32_bf16(c0, wb0, acc, 0,0,0);
                    acc = __builtin_amdgcn_mfma_f32_16x16x32_bf16(c1, wb1, acc, 0,0,0);
                    v2f z01 = {acc[0] + cb1_v[nt], acc[1] + cb1_v[nt]};
                    v2f z23 = {acc[2] + cb1_v[nt], acc[3] + cb1_v[nt]};
                    cwp01 += silu2(z01) * w2c_v[nt];
                    cwp23 += silu2(z23) * w2c_v[nt];
                }
                float cwp[4] = {cwp01.x, cwp01.y, cwp23.x, cwp23.y};
#pragma unroll
                for (int reg = 0; reg < 4; ++reg) {
                    float v = cwp[reg];
                    v += __shfl_xor(v, 1); v += __shfl_xor(v, 2);
                    v += __shfl_xor(v, 4); v += __shfl_xor(v, 8);
                    int er = q4*4 + reg;
                    if (c16 < 3 && er < 12) {
                        int e = e0 + er;
                        int src = s_esrc[e];
                        atomicAdd(&s_shift[src*3 + c16], s_endc[e*3 + c16] * v);
                    }
                }
                // flush m_i for dst d (every tile is a complete dst)
#pragma unroll
                for (int nt = 0; nt < 4; ++nt) {
                    float v = miacc[nt];
                    v += __shfl_xor(v, 16);
                    v += __shfl_xor(v, 32);
                    s_habf[d*136 + 64 + nt*16 + c16] = f2bf(v);
                }
            }
        }

        // prefetch GEMM1 B-frags BEFORE the barrier (waves 0-7)
        s8v bn1[4];
        if (wave < 8) {
#pragma unroll
            for (int kt = 0; kt < 4; ++kt)
                bn1[kt] = *(const s8v*)(wl + 16384 + ((ntA*4+kt)*64 + lane)*8);
        }
        __syncthreads();    // B3

        // ---- node GEMM1 (waves 0-7): wave -> (mtA, ntA); n1bf aliases scratch ----
        if (wave < 8) {
            s8v aA[4];
#pragma unroll
            for (int kt = 0; kt < 4; ++kt)
                aA[kt] = *(const s8v*)(s_habf + (mtA*16 + c16)*136 + kt*32 + q4*8);
            int col = ntA*16 + c16;
            float nbc = s_nb4[l*64 + col];
            v4f acc = {0.f,0.f,0.f,0.f};
#pragma unroll
            for (int kt = 0; kt < 4; ++kt)
                acc = __builtin_amdgcn_mfma_f32_16x16x32_bf16(aA[kt], bn1[kt], acc, 0,0,0);
            v2f z01 = {acc[0] + nbc, acc[1] + nbc};
            v2f z23 = {acc[2] + nbc, acc[3] + nbc};
            unsigned p01 = pk2bfu(silu2(z01)), p23 = pk2bfu(silu2(z23));
            int r0 = mtA*16 + q4*4;
            s_n1bf[(r0+0)*72 + col] = (unsigned short)p01;
            s_n1bf[(r0+1)*72 + col] = (unsigned short)(p01 >> 16);
            s_n1bf[(r0+2)*72 + col] = (unsigned short)p23;
            s_n1bf[(r0+3)*72 + col] = (unsigned short)(p23 >> 16);
        }
        s8v bn2[2];
        if (wave < 8) {
            bn2[0] = *(const s8v*)(wl + 24576 + ((ntA*2+0)*64 + lane)*8);
            bn2[1] = *(const s8v*)(wl + 24576 + ((ntA*2+1)*64 + lane)*8);
        }
        __syncthreads();    // B4

        // ---- node GEMM2 (waves 0-7): h_reg += n1@Wn2 + b2 ----
        if (wave < 8) {
            s8v a0 = *(const s8v*)(s_n1bf + (mtA*16 + c16)*72 +      q4*8);
            s8v a1 = *(const s8v*)(s_n1bf + (mtA*16 + c16)*72 + 32 + q4*8);
            int col = ntA*16 + c16;
            float nb2_v = node_b2[l*64 + col];
            v4f acc = {0.f,0.f,0.f,0.f};
            acc = __builtin_amdgcn_mfma_f32_16x16x32_bf16(a0, bn2[0], acc, 0,0,0);
            acc = __builtin_amdgcn_mfma_f32_16x16x32_bf16(a1, bn2[1], acc, 0,0,0);
#pragma unroll
            for (int reg = 0; reg < 4; ++reg) {
                int row = mtA*16 + q4*4 + reg;
                float hn = h_reg[reg] + acc[reg] + nb2_v;
                h_reg[reg] = hn;
                if (l < NL-1) s_habf[row*136 + col] = f2bf(hn);
                else          out[NN*3 + base*64 + row*64 + col] = hn;
            }
        }
        __syncthreads();    // B5
    }

    // ---------------- epilogue: shift @ inv(lattice) ----------------
    if (tid == 0) {
        float a=s_lat[0],b=s_lat[1],cc=s_lat[2];
        float d=s_lat[3],e=s_lat[4],f =s_lat[5];
        float g=s_lat[6],h2=s_lat[7],i2=s_lat[8];
        float A  =  (e*i2 - f*h2);
        float Bm = -(d*i2 - f*g);
        float C  =  (d*h2 - e*g);
        float det = a*A + b*Bm + cc*C;
        float rd = 1.0f/det;
        s_inv[0] = A*rd;
        s_inv[1] = -(b*i2 - cc*h2)*rd;
        s_inv[2] =  (b*f  - cc*e )*rd;
        s_inv[3] = Bm*rd;
        s_inv[4] =  (a*i2 - cc*g )*rd;
        s_inv[5] = -(a*f  - cc*d )*rd;
        s_inv[6] = C*rd;
        s_inv[7] = -(a*h2 - b*g  )*rd;
        s_inv[8] =  (a*e  - b*d  )*rd;
    }
    __syncthreads();
    if (tid < 96) {
        int r = tid/3, j = tid%3;
        float v = s_shift[r*3+0]*s_inv[0*3+j]
                + s_shift[r*3+1]*s_inv[1*3+j]
                + s_shift[r*3+2]*s_inv[2*3+j];
        out[(base + r)*3 + j] = v;
    }
}

extern "C" void kernel_launch(void* const* d_in, const int* in_sizes, int n_in,
                              void* d_out, int out_size, void* d_ws, size_t ws_size,
                              hipStream_t stream) {
    unsigned short* wbf = (unsigned short*)d_ws;
    prepack_w<<<(4*WPL/8 + 255)/256, 256, 0, stream>>>(
        (const float*)d_in[12], (const float*)d_in[14], (const float*)d_in[16],
        (const float*)d_in[19], (const float*)d_in[21], wbf);
    crystal_fused<<<NB, 1024, 0, stream>>>(
        (const float*)d_in[0],  (const float*)d_in[1],  (const float*)d_in[2],  (const float*)d_in[3],
        (const float*)d_in[6],  (const float*)d_in[7],  (const float*)d_in[8],  (const float*)d_in[9],
        (const float*)d_in[10], (const float*)d_in[11],
        (const float*)d_in[12], (const float*)d_in[13], (const float*)d_in[15],
        (const float*)d_in[17], (const float*)d_in[18],
        (const float*)d_in[19], (const float*)d_in[20], (const float*)d_in[22],
        wbf, (float*)d_out);
}

// Round 7
// 204.436 us; speedup vs baseline: 1.3953x; 1.3953x over previous
//
#include <hip/hip_runtime.h>
#include <hip/hip_bf16.h>
#include <math.h>

#define NB 512
#define NPC 32
#define KNN 12
#define NL 4
#define NN (NB*NPC)
#define WPL 28672   // prepacked bf16 weight elems per layer

typedef float v4f __attribute__((ext_vector_type(4)));
typedef float v2f __attribute__((ext_vector_type(2)));
typedef short s8v __attribute__((ext_vector_type(8)));   // 16 B = 4 VGPRs

// fast silu: ~5 VALU ops (2 transcendental) vs ~10-op exact divide
__device__ __forceinline__ float silu_f(float x) {
    return x * __builtin_amdgcn_rcpf(1.0f + __builtin_amdgcn_exp2f(x * -1.44269504088896341f));
}

// packed-pair silu: muls/adds become v_pk_*_f32 (2 fp32/instr on CDNA4)
__device__ __forceinline__ v2f silu2(v2f x) {
    v2f n = x * -1.44269504088896341f;
    v2f e; e.x = __builtin_amdgcn_exp2f(n.x); e.y = __builtin_amdgcn_exp2f(n.y);
    v2f d = e + 1.0f;
    v2f r; r.x = __builtin_amdgcn_rcpf(d.x); r.y = __builtin_amdgcn_rcpf(d.y);
    return x * r;
}

__device__ __forceinline__ unsigned short f2bf(float x) {
    unsigned u = __float_as_uint(x);
    u += 0x7fffu + ((u >> 16) & 1u);
    return (unsigned short)(u >> 16);
}

// packed 2xfloat -> 2xbf16 in one u32 (v_cvt_pk_bf16_f32)
__device__ __forceinline__ unsigned pk2bf(float a, float b) {
    __hip_bfloat162 t = __float22bfloat162_rn(make_float2(a, b));
    union { __hip_bfloat162 h; unsigned u; } c; c.h = t;
    return c.u;
}
__device__ __forceinline__ unsigned pk2bfu(v2f s) { return pk2bf(s.x, s.y); }

// e/12 for e<384 via magic mul (exact over [0,384))
__device__ __forceinline__ int div12(int e) { return (e * 1366) >> 14; }

// fp32 fallback GEMM (embedding only)
template<int R>
__device__ __forceinline__ void gemm_acc(const float* A, int astride,
                                         const float* __restrict__ Wg,
                                         int K, int lane, float* acc) {
#pragma unroll 2
    for (int kq = 0; kq < (K >> 2); ++kq) {
        float w0 = Wg[(4*kq+0)*64 + lane];
        float w1 = Wg[(4*kq+1)*64 + lane];
        float w2 = Wg[(4*kq+2)*64 + lane];
        float w3 = Wg[(4*kq+3)*64 + lane];
#pragma unroll
        for (int r = 0; r < R; ++r) {
            float4 a = *(const float4*)(A + r*astride + 4*kq);
            acc[r] = fmaf(a.x, w0, acc[r]);
            acc[r] = fmaf(a.y, w1, acc[r]);
            acc[r] = fmaf(a.z, w2, acc[r]);
            acc[r] = fmaf(a.w, w3, acc[r]);
        }
    }
}

// ---------------- prepack (unchanged) ----------------
extern "C" __global__ void prepack_w(const float* __restrict__ edge_w1, const float* __restrict__ edge_w2,
                                     const float* __restrict__ coord_w1, const float* __restrict__ node_w1,
                                     const float* __restrict__ node_w2, unsigned short* __restrict__ wout) {
    int g = blockIdx.x * 256 + threadIdx.x;
    if (g >= 4 * WPL / 8) return;
    int l = (g * 8) / WPL;
    int r = (g * 8) % WPL;
    int base, nKt, mat;
    if      (r < 8192)  { base = 0;     nKt = 2; mat = 0; }
    else if (r < 12288) { base = 8192;  nKt = 2; mat = 1; }
    else if (r < 16384) { base = 12288; nKt = 2; mat = 2; }
    else if (r < 24576) { base = 16384; nKt = 4; mat = 3; }
    else                { base = 24576; nKt = 2; mat = 4; }
    int idx = r - base;
    int lane = (idx >> 3) & 63, t = idx >> 9;
    int kt = t % nKt, nt = t / nKt;
    int k0 = kt*32 + ((lane >> 4) & 3)*8;
    int n  = nt*16 + (lane & 15);
    unsigned short o[8];
#pragma unroll
    for (int j = 0; j < 8; ++j) {
        int k = k0 + j;
        float v;
        if      (mat == 0) v = (n < 64) ? edge_w1[l*193*64 + k*64 + n] : edge_w1[l*193*64 + (64+k)*64 + (n-64)];
        else if (mat == 1) v = edge_w2 [l*4096 + k*64 + n];
        else if (mat == 2) v = coord_w1[l*4096 + k*64 + n];
        else if (mat == 3) v = node_w1 [l*192*64 + k*64 + n];
        else               v = node_w2 [l*4096 + k*64 + n];
        o[j] = f2bf(v);
    }
    *(s8v*)(wout + g*8) = *(s8v*)o;
}

// ---------------- main fused kernel: one block (4 waves) per crystal ----------------
// R20: REVERT to the proven R13 structure (109us dispatch, 256-reg budget,
// zero spill). The R14-R19 TLP arc proved: this kernel needs ~90-130 live
// VGPRs; every >8-waves/CU configuration requires a 64-reg allocation whose
// remat/spill overhead exceeds the TLP gain (R18 +37% VALU, R19 180MB spill).
// On top of R13, three intra-wave wins learned along the way:
//  (1) parallel KNN (4 lanes/row, same lowest-j tie-break; verified R18/R19)
//  (2) pipelined edge phase: dual tile buffers; A(m+1) built between m2(m)'s
//      stores and cw(m)'s reads, covering the lgkm store drain with VALU.
//      W4 -> s_w1r LDS. Net live regs DOWN vs R13 (A(8) replaces H/G(32)).
//  (3) per-wave shift accumulators (s_shift4) kill inter-wave LDS-atomic
//      contention; reduced once in the epilogue.
//  LDS: tiles 16KB->18KB (dbuf), s_dsq aliased onto s_n1bf; total ~71KB.
extern "C" __global__ __launch_bounds__(256, 2)
void crystal_fused(const float* __restrict__ z_nodes, const float* __restrict__ t_in,
                   const float* __restrict__ frac,    const float* __restrict__ lattice,
                   const float* __restrict__ time_w1, const float* __restrict__ time_b1,
                   const float* __restrict__ time_w2, const float* __restrict__ time_b2,
                   const float* __restrict__ emb_w,   const float* __restrict__ emb_b,
                   const float* __restrict__ edge_w1, const float* __restrict__ edge_b1,
                   const float* __restrict__ edge_b2, const float* __restrict__ coord_b1,
                   const float* __restrict__ coord_w2,
                   const float* __restrict__ node_w1, const float* __restrict__ node_b1,
                   const float* __restrict__ node_b2,
                   const unsigned short* __restrict__ wbf,
                   float* __restrict__ out)
{
    __shared__ __align__(16) float s_h[32*65];
    __shared__ __align__(16) unsigned short s_habf[32*136];        // bf16 [h | m_i]
    __shared__ __align__(16) unsigned short s_n1bf[32*72];
    __shared__ __align__(16) float s_hs[32*68];                    // stride 68: rows 16B-aligned
    __shared__ __align__(16) float s_hd[32*68];
    __shared__ __align__(16) unsigned short s_tiles16[9216];       // 18KB: 4 waves x 2 tile buffers / dcf / zbuf
    __shared__ float2 s_emeta[384];                                // {dist_sq, src bits}
    __shared__ float s_endc[384*3];
    __shared__ float s_frac[32][3];
    __shared__ float s_lat[9], s_inv[9];
    __shared__ float s_sinu[64], s_t1[128], s_tf[64];
    __shared__ float s_tb4[NL*64], s_nb4[NL*64];                   // per-layer t-terms (prologue)
    __shared__ float s_shift4[4*96];                               // per-wave shift accumulators
    __shared__ float s_shift[96];                                  // reduced shift (epilogue)
    __shared__ float s_w1r[64];                                    // layer's edge_w1 dist row

    // aliases (lifetimes disjoint, barrier-separated):
    float* dcf = (float*)s_tiles16;                                 // [1024][3] = 12KB, phases 1-2
    float (*s_dsq)[33] = (float(*)[33])s_n1bf;                      // 4224B <= 4608B, phases 1-2

    const int tid  = threadIdx.x;
    const int c    = blockIdx.x;
    const int lane = tid & 63;
    const int wave = tid >> 6;       // 0..3
    const int q4   = lane >> 4;
    const int c16  = lane & 15;
    const int base = c * NPC;

    // ---------------- phase 0 ----------------
    if (tid < 96) {
        ((float*)s_frac)[tid] = frac[base*3 + tid];
    } else if (tid < 105) {
        s_lat[tid-96] = lattice[c*9 + (tid-96)];
    } else if (tid >= 128 && tid < 160) {
        int i = tid - 128;
        float freq = expf((float)i * (-9.210340371976184f / 31.0f));
        float ang  = t_in[c] * freq;
        s_sinu[i]    = sinf(ang);
        s_sinu[i+32] = cosf(ang);
    }
    __syncthreads();

    // ---------------- phase 1: PBC pair distances ----------------
    {
        float l00=s_lat[0],l01=s_lat[1],l02=s_lat[2];
        float l10=s_lat[3],l11=s_lat[4],l12=s_lat[5];
        float l20=s_lat[6],l21=s_lat[7],l22=s_lat[8];
        for (int p = tid; p < 1024; p += 256) {
            int i = p >> 5, j = p & 31;
            float dx = s_frac[i][0]-s_frac[j][0];
            float dy = s_frac[i][1]-s_frac[j][1];
            float dz = s_frac[i][2]-s_frac[j][2];
            dx -= rintf(dx); dy -= rintf(dy); dz -= rintf(dz);
            float cx = dx*l00 + dy*l10 + dz*l20;
            float cy = dx*l01 + dy*l11 + dz*l21;
            float cz = dx*l02 + dy*l12 + dz*l22;
            float dd = cx*cx + cy*cy + cz*cz;
            s_dsq[i][j] = (i==j) ? 3.0e38f : dd;
            dcf[p*3+0]=cx; dcf[p*3+1]=cy; dcf[p*3+2]=cz;
        }
    }
    __syncthreads();

    // ---------------- phase 2: parallel KNN (4 lanes/row, waves 0-1) || time-MLP L1 (waves 2-3) ----------------
    if (tid < 128) {
        int i = tid >> 2, g = tid & 3;
        // each lane owns 8 candidate columns in registers
        float dl0 = s_dsq[i][g*8+0], dl1 = s_dsq[i][g*8+1];
        float dl2 = s_dsq[i][g*8+2], dl3 = s_dsq[i][g*8+3];
        float dl4 = s_dsq[i][g*8+4], dl5 = s_dsq[i][g*8+5];
        float dl6 = s_dsq[i][g*8+6], dl7 = s_dsq[i][g*8+7];
        for (int k = 0; k < KNN; ++k) {
            // local argmin (ascending scan, strict < => lowest j on ties)
            float v = dl0; int jl = g*8;
            if (dl1 < v) { v = dl1; jl = g*8+1; }
            if (dl2 < v) { v = dl2; jl = g*8+2; }
            if (dl3 < v) { v = dl3; jl = g*8+3; }
            if (dl4 < v) { v = dl4; jl = g*8+4; }
            if (dl5 < v) { v = dl5; jl = g*8+5; }
            if (dl6 < v) { v = dl6; jl = g*8+6; }
            if (dl7 < v) { v = dl7; jl = g*8+7; }
            // 4-lane reduce (xor 1/2 stays within the row's lane group)
            float ov; int oj;
            ov = __shfl_xor(v, 1); oj = __shfl_xor(jl, 1);
            if (ov < v || (ov == v && oj < jl)) { v = ov; jl = oj; }
            ov = __shfl_xor(v, 2); oj = __shfl_xor(jl, 2);
            if (ov < v || (ov == v && oj < jl)) { v = ov; jl = oj; }
            // owner removes the winner from its local set
            if ((jl >> 3) == g) {
                int s = jl & 7;
                if      (s == 0) dl0 = 3.9e38f;
                else if (s == 1) dl1 = 3.9e38f;
                else if (s == 2) dl2 = 3.9e38f;
                else if (s == 3) dl3 = 3.9e38f;
                else if (s == 4) dl4 = 3.9e38f;
                else if (s == 5) dl5 = 3.9e38f;
                else if (s == 6) dl6 = 3.9e38f;
                else             dl7 = 3.9e38f;
            }
            if (g == 0) {
                int e = i*KNN + k;
                s_emeta[e] = make_float2(v, __int_as_float(jl));
                int p = (i<<5) + jl;
                s_endc[e*3+0] = dcf[p*3+0];
                s_endc[e*3+1] = dcf[p*3+1];
                s_endc[e*3+2] = dcf[p*3+2];
            }
        }
    } else {
        int jj = tid - 128;
        float p0 = time_b1[jj], p1=0.f, p2=0.f, p3=0.f;
        for (int k = 0; k < 64; k += 4) {
            p0 = fmaf(s_sinu[k+0], time_w1[(k+0)*128+jj], p0);
            p1 = fmaf(s_sinu[k+1], time_w1[(k+1)*128+jj], p1);
            p2 = fmaf(s_sinu[k+2], time_w1[(k+2)*128+jj], p2);
            p3 = fmaf(s_sinu[k+3], time_w1[(k+3)*128+jj], p3);
        }
        s_t1[jj] = silu_f((p0+p1) + (p2+p3));
    }
    __syncthreads();

    // ---------------- phase 3: t_feat ; zero per-wave shift ----------------
    if (tid < 64) {
        float p0=time_b2[tid],p1=0.f,p2=0.f,p3=0.f;
        for (int k = 0; k < 128; k += 4) {
            p0 = fmaf(s_t1[k+0], time_w2[(k+0)*64+tid], p0);
            p1 = fmaf(s_t1[k+1], time_w2[(k+1)*64+tid], p1);
            p2 = fmaf(s_t1[k+2], time_w2[(k+2)*64+tid], p2);
            p3 = fmaf(s_t1[k+3], time_w2[(k+3)*64+tid], p3);
        }
        s_tf[tid] = (p0+p1) + (p2+p3);
    } else {
        for (int q = tid - 64; q < 384; q += 192) s_shift4[q] = 0.0f;
    }
    __syncthreads();

    // ---------------- phase 4: z staging + ALL-layer tb/nb GEMVs (2 tasks/wave) ----------------
    float* zbuf = (float*)s_tiles16;     // [32][128] = 16KB (fits 18KB tile region)
    for (int q = tid; q < 4096; q += 256) zbuf[q] = z_nodes[base*128 + q];
#pragma unroll
    for (int it = 0; it < 2; ++it) {
        int t = wave + it*4;
        int lt = t >> 1, kind = t & 1;
        const float* Wt = kind ? (node_w1 + lt*192*64 + 128*64) : (edge_w1 + lt*193*64 + 129*64);
        const float* bb = kind ? (node_b1 + lt*64) : (edge_b1 + lt*64);
        float p0 = bb[lane], p1=0.f, p2=0.f, p3=0.f;
        for (int k = 0; k < 64; k += 4) {
            p0 = fmaf(s_tf[k+0], Wt[(k+0)*64 + lane], p0);
            p1 = fmaf(s_tf[k+1], Wt[(k+1)*64 + lane], p1);
            p2 = fmaf(s_tf[k+2], Wt[(k+2)*64 + lane], p2);
            p3 = fmaf(s_tf[k+3], Wt[(k+3)*64 + lane], p3);
        }
        float v = (p0+p1) + (p2+p3);
        if (kind) s_nb4[lt*64 + lane] = v;
        else      s_tb4[lt*64 + lane] = v;
    }
    __syncthreads();

    // ---------------- phase 5: node embedding (8 rows/wave) ----------------
    {
        float acc[8];
#pragma unroll
        for (int r = 0; r < 8; ++r) acc[r] = emb_b[lane];
        gemm_acc<8>(zbuf + (wave*8)*128, 128, emb_w, 128, lane, acc);
#pragma unroll
        for (int r = 0; r < 8; ++r) {
            int row = wave*8 + r;
            s_h[row*65 + lane] = acc[r];
            s_habf[row*136 + lane] = f2bf(acc[r]);
        }
    }
    __syncthreads();    // habf ready for layer 0 step A

    // ---------------- EGNN layers ----------------
    for (int l = 0; l < NL; ++l) {
        const unsigned short* wl = wbf + l*WPL;

        // stage dist-row weights to LDS (readers wait on B2)
        if (tid < 64) s_w1r[tid] = edge_w1[l*193*64 + 128*64 + tid];

        float b2e_v[4], cb1_v[4], w2c_v[4];
#pragma unroll
        for (int nt = 0; nt < 4; ++nt) {
            b2e_v[nt] = edge_b2 [l*64 + nt*16 + c16];
            cb1_v[nt] = coord_b1[l*64 + nt*16 + c16];
            w2c_v[nt] = coord_w2[l*64 + nt*16 + c16];
        }

        // hoisted edge-phase weights: issue global loads early, use after step A
        s8v w2f[8], wc1f[8];
#pragma unroll
        for (int nt = 0; nt < 4; ++nt)
#pragma unroll
            for (int kt = 0; kt < 2; ++kt) {
                w2f [nt*2+kt] = *(const s8v*)(wl +  8192 + ((nt*2+kt)*64 + lane)*8);
                wc1f[nt*2+kt] = *(const s8v*)(wl + 12288 + ((nt*2+kt)*64 + lane)*8);
            }

        // ---- step A: wave w -> hs ntile w AND hd ntile w (shared A-frags) ----
        {
            s8v a[2][2];
#pragma unroll
            for (int mt = 0; mt < 2; ++mt)
#pragma unroll
                for (int kt = 0; kt < 2; ++kt)
                    a[mt][kt] = *(const s8v*)(s_habf + (mt*16 + c16)*136 + kt*32 + q4*8);
            v4f accS[2] = {{0.f,0.f,0.f,0.f},{0.f,0.f,0.f,0.f}};
            v4f accD[2] = {{0.f,0.f,0.f,0.f},{0.f,0.f,0.f,0.f}};
#pragma unroll
            for (int kt = 0; kt < 2; ++kt) {
                s8v bS = *(const s8v*)(wl + ((wave*2+kt)*64 + lane)*8);
                s8v bD = *(const s8v*)(wl + (((wave+4)*2+kt)*64 + lane)*8);
#pragma unroll
                for (int mt = 0; mt < 2; ++mt) {
                    accS[mt] = __builtin_amdgcn_mfma_f32_16x16x32_bf16(a[mt][kt], bS, accS[mt], 0, 0, 0);
                    accD[mt] = __builtin_amdgcn_mfma_f32_16x16x32_bf16(a[mt][kt], bD, accD[mt], 0, 0, 0);
                }
            }
            int col = wave*16 + c16;
            float tbv = s_tb4[l*64 + col];
#pragma unroll
            for (int mt = 0; mt < 2; ++mt)
#pragma unroll
                for (int reg = 0; reg < 4; ++reg) {
                    int row = mt*16 + q4*4 + reg;
                    s_hs[row*68 + col] = accS[mt][reg];
                    s_hd[row*68 + col] = accD[mt][reg] + tbv;
                }
        }
        __syncthreads();    // B2

        // ---- edge phase (pipelined): wave owns 96 edges, 6 tiles of 16, dual tile buffers ----
        {
            unsigned short* tbase = s_tiles16 + wave*2304;   // 2 buffers x 1152 shorts
            float* myshift = s_shift4 + wave*96;
            float miacc[4][2];   // rolling 2-slot window (slot = dst&1)
#pragma unroll
            for (int a2 = 0; a2 < 4; ++a2) { miacc[a2][0] = 0.f; miacc[a2][1] = 0.f; }

            auto flushd = [&](int d) {
                int s = d & 1;
#pragma unroll
                for (int nt = 0; nt < 4; ++nt) {
                    float v = miacc[nt][s];
                    v += __shfl_xor(v, 16);
                    v += __shfl_xor(v, 32);
                    s_habf[(wave*8 + d)*136 + 64 + nt*16 + c16] = f2bf(v);
                    miacc[nt][s] = 0.f;
                }
            };

            // all 6 tiles' edge meta upfront
            float2 me0 = s_emeta[wave*96 +  0 + c16];
            float2 me1 = s_emeta[wave*96 + 16 + c16];
            float2 me2 = s_emeta[wave*96 + 32 + c16];
            float2 me3 = s_emeta[wave*96 + 48 + c16];
            float2 me4 = s_emeta[wave*96 + 64 + c16];
            float2 me5 = s_emeta[wave*96 + 80 + c16];

            union S8 { s8v v; unsigned u[4]; } A0, A1;
            // prologue: build A for tile 0
            {
                int srcn = __float_as_int(me0.y);
                int dstn = div12(wave*96 + c16);
                const float* hsr = s_hs + srcn*68;
                const float* hdr = s_hd + dstn*68;
                const float dq = me0.x;
#pragma unroll
                for (int g2 = 0; g2 < 4; ++g2) {
                    int off = ((g2 & 2) ? 32 : 0) + ((g2 & 1) ? 4 : 0) + q4*8;
                    float4 Hv = *(const float4*)(hsr + off);
                    float4 Gv = *(const float4*)(hdr + off);
                    float4 Wv = *(const float4*)(s_w1r + off);
                    v2f t0 = {Hv.x + Gv.x + Wv.x*dq, Hv.y + Gv.y + Wv.y*dq};
                    v2f t1 = {Hv.z + Gv.z + Wv.z*dq, Hv.w + Gv.w + Wv.w*dq};
                    unsigned lo  = pk2bfu(silu2(t0));
                    unsigned hi2 = pk2bfu(silu2(t1));
                    if (g2 < 2) { A0.u[g2*2] = lo; A0.u[g2*2+1] = hi2; }
                    else        { A1.u[(g2-2)*2] = lo; A1.u[(g2-2)*2+1] = hi2; }
                }
            }

#pragma unroll
            for (int m = 0; m < 6; ++m) {
                const int e0g = wave*96 + m*16;
                unsigned short* tile = tbase + (m & 1)*1152;

                // m2 = silu(m1@W2 + b2): consumes A(m); stores into tile[m&1]
                const int dlo = (m < 3) ? m : m + 1;           // local dst ids {dlo, dlo+1}
                const int thr = 3 - (m % 3);                   // q4>=thr -> upper dst
                const int slo = dlo & 1;
#pragma unroll
                for (int nt = 0; nt < 4; ++nt) {
                    v4f acc = {0.f,0.f,0.f,0.f};
                    acc = __builtin_amdgcn_mfma_f32_16x16x32_bf16(A0.v, w2f[nt*2+0], acc, 0,0,0);
                    acc = __builtin_amdgcn_mfma_f32_16x16x32_bf16(A1.v, w2f[nt*2+1], acc, 0,0,0);
                    int col = nt*16 + c16;
                    v2f z01 = {acc[0] + b2e_v[nt], acc[1] + b2e_v[nt]};
                    v2f z23 = {acc[2] + b2e_v[nt], acc[3] + b2e_v[nt]};
                    v2f s01 = silu2(z01), s23 = silu2(z23);
                    unsigned p01 = pk2bfu(s01), p23 = pk2bfu(s23);
                    tile[(q4*4 + 0)*72 + col] = (unsigned short)p01;
                    tile[(q4*4 + 1)*72 + col] = (unsigned short)(p01 >> 16);
                    tile[(q4*4 + 2)*72 + col] = (unsigned short)p23;
                    tile[(q4*4 + 3)*72 + col] = (unsigned short)(p23 >> 16);
                    float msum = (s01.x + s01.y) + (s23.x + s23.y);
                    bool hi = (q4 >= thr);
                    miacc[nt][slo]     += hi ? 0.f : msum;
                    miacc[nt][slo ^ 1] += hi ? msum : 0.f;
                }

                // build A(m+1) here: its VALU chain covers the tile-store drain
                if (m < 5) {
                    float2 men = (m==0) ? me1 : (m==1) ? me2 : (m==2) ? me3
                               : (m==3) ? me4 : me5;
                    int srcn = __float_as_int(men.y);
                    int dstn = div12(e0g + 16 + c16);
                    const float* hsr = s_hs + srcn*68;
                    const float* hdr = s_hd + dstn*68;
                    const float dqn = men.x;
#pragma unroll
                    for (int g2 = 0; g2 < 4; ++g2) {
                        int off = ((g2 & 2) ? 32 : 0) + ((g2 & 1) ? 4 : 0) + q4*8;
                        float4 Hv = *(const float4*)(hsr + off);
                        float4 Gv = *(const float4*)(hdr + off);
                        float4 Wv = *(const float4*)(s_w1r + off);
                        v2f t0 = {Hv.x + Gv.x + Wv.x*dqn, Hv.y + Gv.y + Wv.y*dqn};
                        v2f t1 = {Hv.z + Gv.z + Wv.z*dqn, Hv.w + Gv.w + Wv.w*dqn};
                        unsigned lo  = pk2bfu(silu2(t0));
                        unsigned hi2 = pk2bfu(silu2(t1));
                        if (g2 < 2) { A0.u[g2*2] = lo; A0.u[g2*2+1] = hi2; }
                        else        { A1.u[(g2-2)*2] = lo; A1.u[(g2-2)*2+1] = hi2; }
                    }
                }

                asm volatile("s_waitcnt lgkmcnt(0)" ::: "memory");
                s8v c0 = *(const s8v*)(tile + c16*72 +      q4*8);
                s8v c1 = *(const s8v*)(tile + c16*72 + 32 + q4*8);
                // cw = silu(m2@Wc1 + cb1) . w2c — packed pairs
                v2f cwp01 = {0.f, 0.f}, cwp23 = {0.f, 0.f};
#pragma unroll
                for (int nt = 0; nt < 4; ++nt) {
                    v4f acc = {0.f,0.f,0.f,0.f};
                    acc = __builtin_amdgcn_mfma_f32_16x16x32_bf16(c0, wc1f[nt*2+0], acc, 0,0,0);
                    acc = __builtin_amdgcn_mfma_f32_16x16x32_bf16(c1, wc1f[nt*2+1], acc, 0,0,0);
                    v2f z01 = {acc[0] + cb1_v[nt], acc[1] + cb1_v[nt]};
                    v2f z23 = {acc[2] + cb1_v[nt], acc[3] + cb1_v[nt]};
                    cwp01 += silu2(z01) * w2c_v[nt];
                    cwp23 += silu2(z23) * w2c_v[nt];
                }
                float cwp[4] = {cwp01.x, cwp01.y, cwp23.x, cwp23.y};
#pragma unroll
                for (int reg = 0; reg < 4; ++reg) {
                    float v = cwp[reg];
                    v += __shfl_xor(v, 1); v += __shfl_xor(v, 2);
                    v += __shfl_xor(v, 4); v += __shfl_xor(v, 8);
                    int e = e0g + q4*4 + reg;
                    if (c16 < 3) {
                        int src = __float_as_int(s_emeta[e].y);
                        atomicAdd(&myshift[src*3 + c16], s_endc[e*3 + c16] * v);
                    }
                }
                // flush completed dsts (dst d complete iff (d+1)*12 <= m*16+16)
                if (m == 0) { flushd(0); }
                else if (m == 1) { flushd(1); }
                else if (m == 2) { flushd(2); flushd(3); }
                else if (m == 3) { flushd(4); }
                else if (m == 4) { flushd(5); }
                else             { flushd(6); flushd(7); }
            }
        }

        // prefetch GEMM1 B-frags BEFORE the barrier (2 nt-sets)
        const int mtA = wave & 1, nt0 = wave >> 1, nt1 = (wave >> 1) + 2;
        s8v bn1[8];
#pragma unroll
        for (int kt = 0; kt < 4; ++kt) {
            bn1[kt]   = *(const s8v*)(wl + 16384 + ((nt0*4+kt)*64 + lane)*8);
            bn1[4+kt] = *(const s8v*)(wl + 16384 + ((nt1*4+kt)*64 + lane)*8);
        }
        __syncthreads();    // B3

        // ---- node GEMM1: wave -> (mtA, nt0) and (mtA, nt1), shared A-frags ----
        {
            s8v aA[4];
#pragma unroll
            for (int kt = 0; kt < 4; ++kt)
                aA[kt] = *(const s8v*)(s_habf + (mtA*16 + c16)*136 + kt*32 + q4*8);
#pragma unroll
            for (int it = 0; it < 2; ++it) {
                int nt = it ? nt1 : nt0;
                int col = nt*16 + c16;
                float nbc = s_nb4[l*64 + col];
                v4f acc = {0.f,0.f,0.f,0.f};
#pragma unroll
                for (int kt = 0; kt < 4; ++kt)
                    acc = __builtin_amdgcn_mfma_f32_16x16x32_bf16(aA[kt], bn1[it*4+kt], acc, 0,0,0);
                v2f z01 = {acc[0] + nbc, acc[1] + nbc};
                v2f z23 = {acc[2] + nbc, acc[3] + nbc};
                unsigned p01 = pk2bfu(silu2(z01)), p23 = pk2bfu(silu2(z23));
                int r0 = mtA*16 + q4*4;
                s_n1bf[(r0+0)*72 + col] = (unsigned short)p01;
                s_n1bf[(r0+1)*72 + col] = (unsigned short)(p01 >> 16);
                s_n1bf[(r0+2)*72 + col] = (unsigned short)p23;
                s_n1bf[(r0+3)*72 + col] = (unsigned short)(p23 >> 16);
            }
        }
        // prefetch GEMM2 B-frags before B4
        s8v bn2[4];
        bn2[0] = *(const s8v*)(wl + 24576 + ((nt0*2+0)*64 + lane)*8);
        bn2[1] = *(const s8v*)(wl + 24576 + ((nt0*2+1)*64 + lane)*8);
        bn2[2] = *(const s8v*)(wl + 24576 + ((nt1*2+0)*64 + lane)*8);
        bn2[3] = *(const s8v*)(wl + 24576 + ((nt1*2+1)*64 + lane)*8);
        __syncthreads();    // B4

        // ---- node GEMM2: h += n1@Wn2 + b2, two nt sub-tiles, shared A-frags ----
        {
            s8v a0 = *(const s8v*)(s_n1bf + (mtA*16 + c16)*72 +      q4*8);
            s8v a1 = *(const s8v*)(s_n1bf + (mtA*16 + c16)*72 + 32 + q4*8);
#pragma unroll
            for (int it = 0; it < 2; ++it) {
                int nt = it ? nt1 : nt0;
                int col = nt*16 + c16;
                float nb2_v = node_b2[l*64 + col];
                v4f acc = {0.f,0.f,0.f,0.f};
                acc = __builtin_amdgcn_mfma_f32_16x16x32_bf16(a0, bn2[it*2+0], acc, 0,0,0);
                acc = __builtin_amdgcn_mfma_f32_16x16x32_bf16(a1, bn2[it*2+1], acc, 0,0,0);
#pragma unroll
                for (int reg = 0; reg < 4; ++reg) {
                    int row = mtA*16 + q4*4 + reg;
                    float hn = s_h[row*65 + col] + acc[reg] + nb2_v;
                    s_h[row*65 + col] = hn;
                    s_habf[row*136 + col] = f2bf(hn);
                }
            }
        }
        __syncthreads();    // B5
    }

    // ---------------- epilogue ----------------
    if (tid == 0) {
        float a=s_lat[0],b=s_lat[1],cc=s_lat[2];
        float d=s_lat[3],e=s_lat[4],f =s_lat[5];
        float g=s_lat[6],h2=s_lat[7],i2=s_lat[8];
        float A  =  (e*i2 - f*h2);
        float Bm = -(d*i2 - f*g);
        float C  =  (d*h2 - e*g);
        float det = a*A + b*Bm + cc*C;
        float rd = 1.0f/det;
        s_inv[0] = A*rd;
        s_inv[1] = -(b*i2 - cc*h2)*rd;
        s_inv[2] =  (b*f  - cc*e )*rd;
        s_inv[3] = Bm*rd;
        s_inv[4] =  (a*i2 - cc*g )*rd;
        s_inv[5] = -(a*f  - cc*d )*rd;
        s_inv[6] = C*rd;
        s_inv[7] = -(a*h2 - b*g  )*rd;
        s_inv[8] =  (a*e  - b*d  )*rd;
    }
    if (tid < 96) {
        s_shift[tid] = s_shift4[tid] + s_shift4[96 + tid]
                     + s_shift4[192 + tid] + s_shift4[288 + tid];
    }
    __syncthreads();
    if (tid < 96) {
        int r = tid/3, j = tid%3;
        float v = s_shift[r*3+0]*s_inv[0*3+j]
                + s_shift[r*3+1]*s_inv[1*3+j]
                + s_shift[r*3+2]*s_inv[2*3+j];
        out[(base + r)*3 + j] = v;
    }
    for (int q = tid; q < 2048; q += 256) {
        int row = q >> 6, colq = q & 63;
        out[NN*3 + base*64 + q] = s_h[row*65 + colq];
    }
}

extern "C" void kernel_launch(void* const* d_in, const int* in_sizes, int n_in,
                              void* d_out, int out_size, void* d_ws, size_t ws_size,
                              hipStream_t stream) {
    unsigned short* wbf = (unsigned short*)d_ws;
    prepack_w<<<(4*WPL/8 + 255)/256, 256, 0, stream>>>(
        (const float*)d_in[12], (const float*)d_in[14], (const float*)d_in[16],
        (const float*)d_in[19], (const float*)d_in[21], wbf);
    crystal_fused<<<NB, 256, 0, stream>>>(
        (const float*)d_in[0],  (const float*)d_in[1],  (const float*)d_in[2],  (const float*)d_in[3],
        (const float*)d_in[6],  (const float*)d_in[7],  (const float*)d_in[8],  (const float*)d_in[9],
        (const float*)d_in[10], (const float*)d_in[11],
        (const float*)d_in[12], (const float*)d_in[13], (const float*)d_in[15],
        (const float*)d_in[17], (const float*)d_in[18],
        (const float*)d_in[19], (const float*)d_in[20], (const float*)d_in[22],
        wbf, (float*)d_out);
}

// Round 8
// 200.955 us; speedup vs baseline: 1.4195x; 1.0173x over previous
//
#include <hip/hip_runtime.h>
#include <hip/hip_bf16.h>
#include <math.h>

#define NB 512
#define NPC 32
#define KNN 12
#define NL 4
#define NN (NB*NPC)
#define WPL 28672   // prepacked bf16 weight elems per layer

typedef float v4f __attribute__((ext_vector_type(4)));
typedef float v2f __attribute__((ext_vector_type(2)));
typedef short s8v __attribute__((ext_vector_type(8)));   // 16 B = 4 VGPRs

// fast silu: ~5 VALU ops (2 transcendental) vs ~10-op exact divide
__device__ __forceinline__ float silu_f(float x) {
    return x * __builtin_amdgcn_rcpf(1.0f + __builtin_amdgcn_exp2f(x * -1.44269504088896341f));
}

// packed-pair silu: muls/adds become v_pk_*_f32 (2 fp32/instr on CDNA4)
__device__ __forceinline__ v2f silu2(v2f x) {
    v2f n = x * -1.44269504088896341f;
    v2f e; e.x = __builtin_amdgcn_exp2f(n.x); e.y = __builtin_amdgcn_exp2f(n.y);
    v2f d = e + 1.0f;
    v2f r; r.x = __builtin_amdgcn_rcpf(d.x); r.y = __builtin_amdgcn_rcpf(d.y);
    return x * r;
}

__device__ __forceinline__ unsigned short f2bf(float x) {
    unsigned u = __float_as_uint(x);
    u += 0x7fffu + ((u >> 16) & 1u);
    return (unsigned short)(u >> 16);
}

// packed 2xfloat -> 2xbf16 in one u32 (v_cvt_pk_bf16_f32)
__device__ __forceinline__ unsigned pk2bf(float a, float b) {
    __hip_bfloat162 t = __float22bfloat162_rn(make_float2(a, b));
    union { __hip_bfloat162 h; unsigned u; } c; c.h = t;
    return c.u;
}
__device__ __forceinline__ unsigned pk2bfu(v2f s) { return pk2bf(s.x, s.y); }

// e/12 for e<384 via magic mul (exact over [0,384))
__device__ __forceinline__ int div12(int e) { return (e * 1366) >> 14; }

// fp32 fallback GEMM (embedding only)
template<int R>
__device__ __forceinline__ void gemm_acc(const float* A, int astride,
                                         const float* __restrict__ Wg,
                                         int K, int lane, float* acc) {
#pragma unroll 2
    for (int kq = 0; kq < (K >> 2); ++kq) {
        float w0 = Wg[(4*kq+0)*64 + lane];
        float w1 = Wg[(4*kq+1)*64 + lane];
        float w2 = Wg[(4*kq+2)*64 + lane];
        float w3 = Wg[(4*kq+3)*64 + lane];
#pragma unroll
        for (int r = 0; r < R; ++r) {
            float4 a = *(const float4*)(A + r*astride + 4*kq);
            acc[r] = fmaf(a.x, w0, acc[r]);
            acc[r] = fmaf(a.y, w1, acc[r]);
            acc[r] = fmaf(a.z, w2, acc[r]);
            acc[r] = fmaf(a.w, w3, acc[r]);
        }
    }
}

// ---------------- prepack (unchanged) ----------------
extern "C" __global__ void prepack_w(const float* __restrict__ edge_w1, const float* __restrict__ edge_w2,
                                     const float* __restrict__ coord_w1, const float* __restrict__ node_w1,
                                     const float* __restrict__ node_w2, unsigned short* __restrict__ wout) {
    int g = blockIdx.x * 256 + threadIdx.x;
    if (g >= 4 * WPL / 8) return;
    int l = (g * 8) / WPL;
    int r = (g * 8) % WPL;
    int base, nKt, mat;
    if      (r < 8192)  { base = 0;     nKt = 2; mat = 0; }
    else if (r < 12288) { base = 8192;  nKt = 2; mat = 1; }
    else if (r < 16384) { base = 12288; nKt = 2; mat = 2; }
    else if (r < 24576) { base = 16384; nKt = 4; mat = 3; }
    else                { base = 24576; nKt = 2; mat = 4; }
    int idx = r - base;
    int lane = (idx >> 3) & 63, t = idx >> 9;
    int kt = t % nKt, nt = t / nKt;
    int k0 = kt*32 + ((lane >> 4) & 3)*8;
    int n  = nt*16 + (lane & 15);
    unsigned short o[8];
#pragma unroll
    for (int j = 0; j < 8; ++j) {
        int k = k0 + j;
        float v;
        if      (mat == 0) v = (n < 64) ? edge_w1[l*193*64 + k*64 + n] : edge_w1[l*193*64 + (64+k)*64 + (n-64)];
        else if (mat == 1) v = edge_w2 [l*4096 + k*64 + n];
        else if (mat == 2) v = coord_w1[l*4096 + k*64 + n];
        else if (mat == 3) v = node_w1 [l*192*64 + k*64 + n];
        else               v = node_w2 [l*4096 + k*64 + n];
        o[j] = f2bf(v);
    }
    *(s8v*)(wout + g*8) = *(s8v*)o;
}

// ---------------- main fused kernel: one block (4 waves) per crystal ----------------
// R21: de-bundle R20. R20's "pipelined" edge phase REGRESSED (114 vs 109us):
// it shortened the H/G load-to-use distance (R13 issued them a full m2-phase
// early into registers) and added s_w1r LDS reads where R13 held W4 in regs.
// Restore R13's edge phase EXACTLY. Keep the two sound components:
//  (1) parallel KNN (4 lanes/row, lowest-j tie-break; verified R18/R19/R20)
//  (2) per-wave shift accumulators (no LDS-atomic contention; epilogue reduce)
//  (3) s_dsq aliased onto s_n1bf (disjoint lifetimes): LDS ~69KB.
extern "C" __global__ __launch_bounds__(256, 2)
void crystal_fused(const float* __restrict__ z_nodes, const float* __restrict__ t_in,
                   const float* __restrict__ frac,    const float* __restrict__ lattice,
                   const float* __restrict__ time_w1, const float* __restrict__ time_b1,
                   const float* __restrict__ time_w2, const float* __restrict__ time_b2,
                   const float* __restrict__ emb_w,   const float* __restrict__ emb_b,
                   const float* __restrict__ edge_w1, const float* __restrict__ edge_b1,
                   const float* __restrict__ edge_b2, const float* __restrict__ coord_b1,
                   const float* __restrict__ coord_w2,
                   const float* __restrict__ node_w1, const float* __restrict__ node_b1,
                   const float* __restrict__ node_b2,
                   const unsigned short* __restrict__ wbf,
                   float* __restrict__ out)
{
    __shared__ __align__(16) float s_h[32*65];
    __shared__ __align__(16) unsigned short s_habf[32*136];        // bf16 [h | m_i]
    __shared__ __align__(16) unsigned short s_n1bf[32*72];
    __shared__ __align__(16) float s_hs[32*68];                    // stride 68: rows 16B-aligned
    __shared__ __align__(16) float s_hd[32*68];
    __shared__ __align__(16) unsigned short s_tiles16[8192];       // 16KB: per-wave m2 tiles (4x1152) / dcf / zbuf
    __shared__ float2 s_emeta[384];                                // {dist_sq, src bits}
    __shared__ float s_endc[384*3];
    __shared__ float s_frac[32][3];
    __shared__ float s_lat[9], s_inv[9];
    __shared__ float s_sinu[64], s_t1[128], s_tf[64];
    __shared__ float s_tb4[NL*64], s_nb4[NL*64];                   // per-layer t-terms (prologue)
    __shared__ float s_shift4[4*96];                               // per-wave shift accumulators
    __shared__ float s_shift[96];                                  // reduced shift (epilogue)

    // alias (lifetimes disjoint, barrier-separated): s_dsq lives in s_n1bf
    float (*s_dsq)[33] = (float(*)[33])s_n1bf;                      // 4224B <= 4608B, phases 1-2

    const int tid  = threadIdx.x;
    const int c    = blockIdx.x;
    const int lane = tid & 63;
    const int wave = tid >> 6;       // 0..3
    const int q4   = lane >> 4;
    const int c16  = lane & 15;
    const int base = c * NPC;

    // ---------------- phase 0 ----------------
    if (tid < 96) {
        ((float*)s_frac)[tid] = frac[base*3 + tid];
    } else if (tid < 105) {
        s_lat[tid-96] = lattice[c*9 + (tid-96)];
    } else if (tid >= 128 && tid < 160) {
        int i = tid - 128;
        float freq = expf((float)i * (-9.210340371976184f / 31.0f));
        float ang  = t_in[c] * freq;
        s_sinu[i]    = sinf(ang);
        s_sinu[i+32] = cosf(ang);
    }
    __syncthreads();

    // ---------------- phase 1: PBC pair distances ----------------
    float* dcf = (float*)s_tiles16;      // [1024][3] = 12KB
    {
        float l00=s_lat[0],l01=s_lat[1],l02=s_lat[2];
        float l10=s_lat[3],l11=s_lat[4],l12=s_lat[5];
        float l20=s_lat[6],l21=s_lat[7],l22=s_lat[8];
        for (int p = tid; p < 1024; p += 256) {
            int i = p >> 5, j = p & 31;
            float dx = s_frac[i][0]-s_frac[j][0];
            float dy = s_frac[i][1]-s_frac[j][1];
            float dz = s_frac[i][2]-s_frac[j][2];
            dx -= rintf(dx); dy -= rintf(dy); dz -= rintf(dz);
            float cx = dx*l00 + dy*l10 + dz*l20;
            float cy = dx*l01 + dy*l11 + dz*l21;
            float cz = dx*l02 + dy*l12 + dz*l22;
            float dd = cx*cx + cy*cy + cz*cz;
            s_dsq[i][j] = (i==j) ? 3.0e38f : dd;
            dcf[p*3+0]=cx; dcf[p*3+1]=cy; dcf[p*3+2]=cz;
        }
    }
    __syncthreads();

    // ---------------- phase 2: parallel KNN (4 lanes/row, waves 0-1) || time-MLP L1 (waves 2-3) ----------------
    if (tid < 128) {
        int i = tid >> 2, g = tid & 3;
        // each lane owns 8 candidate columns in registers
        float dl0 = s_dsq[i][g*8+0], dl1 = s_dsq[i][g*8+1];
        float dl2 = s_dsq[i][g*8+2], dl3 = s_dsq[i][g*8+3];
        float dl4 = s_dsq[i][g*8+4], dl5 = s_dsq[i][g*8+5];
        float dl6 = s_dsq[i][g*8+6], dl7 = s_dsq[i][g*8+7];
        for (int k = 0; k < KNN; ++k) {
            // local argmin (ascending scan, strict < => lowest j on ties)
            float v = dl0; int jl = g*8;
            if (dl1 < v) { v = dl1; jl = g*8+1; }
            if (dl2 < v) { v = dl2; jl = g*8+2; }
            if (dl3 < v) { v = dl3; jl = g*8+3; }
            if (dl4 < v) { v = dl4; jl = g*8+4; }
            if (dl5 < v) { v = dl5; jl = g*8+5; }
            if (dl6 < v) { v = dl6; jl = g*8+6; }
            if (dl7 < v) { v = dl7; jl = g*8+7; }
            // 4-lane reduce (xor 1/2 stays within the row's lane group)
            float ov; int oj;
            ov = __shfl_xor(v, 1); oj = __shfl_xor(jl, 1);
            if (ov < v || (ov == v && oj < jl)) { v = ov; jl = oj; }
            ov = __shfl_xor(v, 2); oj = __shfl_xor(jl, 2);
            if (ov < v || (ov == v && oj < jl)) { v = ov; jl = oj; }
            // owner removes the winner from its local set
            if ((jl >> 3) == g) {
                int s = jl & 7;
                if      (s == 0) dl0 = 3.9e38f;
                else if (s == 1) dl1 = 3.9e38f;
                else if (s == 2) dl2 = 3.9e38f;
                else if (s == 3) dl3 = 3.9e38f;
                else if (s == 4) dl4 = 3.9e38f;
                else if (s == 5) dl5 = 3.9e38f;
                else if (s == 6) dl6 = 3.9e38f;
                else             dl7 = 3.9e38f;
            }
            if (g == 0) {
                int e = i*KNN + k;
                s_emeta[e] = make_float2(v, __int_as_float(jl));
                int p = (i<<5) + jl;
                s_endc[e*3+0] = dcf[p*3+0];
                s_endc[e*3+1] = dcf[p*3+1];
                s_endc[e*3+2] = dcf[p*3+2];
            }
        }
    } else {
        int jj = tid - 128;
        float p0 = time_b1[jj], p1=0.f, p2=0.f, p3=0.f;
        for (int k = 0; k < 64; k += 4) {
            p0 = fmaf(s_sinu[k+0], time_w1[(k+0)*128+jj], p0);
            p1 = fmaf(s_sinu[k+1], time_w1[(k+1)*128+jj], p1);
            p2 = fmaf(s_sinu[k+2], time_w1[(k+2)*128+jj], p2);
            p3 = fmaf(s_sinu[k+3], time_w1[(k+3)*128+jj], p3);
        }
        s_t1[jj] = silu_f((p0+p1) + (p2+p3));
    }
    __syncthreads();

    // ---------------- phase 3: t_feat ; zero per-wave shift ----------------
    if (tid < 64) {
        float p0=time_b2[tid],p1=0.f,p2=0.f,p3=0.f;
        for (int k = 0; k < 128; k += 4) {
            p0 = fmaf(s_t1[k+0], time_w2[(k+0)*64+tid], p0);
            p1 = fmaf(s_t1[k+1], time_w2[(k+1)*64+tid], p1);
            p2 = fmaf(s_t1[k+2], time_w2[(k+2)*64+tid], p2);
            p3 = fmaf(s_t1[k+3], time_w2[(k+3)*64+tid], p3);
        }
        s_tf[tid] = (p0+p1) + (p2+p3);
    } else {
        for (int q = tid - 64; q < 384; q += 192) s_shift4[q] = 0.0f;
    }
    __syncthreads();

    // ---------------- phase 4: z staging + ALL-layer tb/nb GEMVs (2 tasks/wave) ----------------
    float* zbuf = (float*)s_tiles16;     // [32][128] = 16KB
    for (int q = tid; q < 4096; q += 256) zbuf[q] = z_nodes[base*128 + q];
#pragma unroll
    for (int it = 0; it < 2; ++it) {
        int t = wave + it*4;
        int lt = t >> 1, kind = t & 1;
        const float* Wt = kind ? (node_w1 + lt*192*64 + 128*64) : (edge_w1 + lt*193*64 + 129*64);
        const float* bb = kind ? (node_b1 + lt*64) : (edge_b1 + lt*64);
        float p0 = bb[lane], p1=0.f, p2=0.f, p3=0.f;
        for (int k = 0; k < 64; k += 4) {
            p0 = fmaf(s_tf[k+0], Wt[(k+0)*64 + lane], p0);
            p1 = fmaf(s_tf[k+1], Wt[(k+1)*64 + lane], p1);
            p2 = fmaf(s_tf[k+2], Wt[(k+2)*64 + lane], p2);
            p3 = fmaf(s_tf[k+3], Wt[(k+3)*64 + lane], p3);
        }
        float v = (p0+p1) + (p2+p3);
        if (kind) s_nb4[lt*64 + lane] = v;
        else      s_tb4[lt*64 + lane] = v;
    }
    __syncthreads();

    // ---------------- phase 5: node embedding (8 rows/wave) ----------------
    {
        float acc[8];
#pragma unroll
        for (int r = 0; r < 8; ++r) acc[r] = emb_b[lane];
        gemm_acc<8>(zbuf + (wave*8)*128, 128, emb_w, 128, lane, acc);
#pragma unroll
        for (int r = 0; r < 8; ++r) {
            int row = wave*8 + r;
            s_h[row*65 + lane] = acc[r];
            s_habf[row*136 + lane] = f2bf(acc[r]);
        }
    }
    __syncthreads();    // habf ready for layer 0 step A

    // ---------------- EGNN layers ----------------
    for (int l = 0; l < NL; ++l) {
        const unsigned short* wl = wbf + l*WPL;
        const float* w1row = edge_w1 + l*193*64 + 128*64;   // dist^2 weight row
        float b2e_v[4], cb1_v[4], w2c_v[4];
#pragma unroll
        for (int nt = 0; nt < 4; ++nt) {
            b2e_v[nt] = edge_b2 [l*64 + nt*16 + c16];
            cb1_v[nt] = coord_b1[l*64 + nt*16 + c16];
            w2c_v[nt] = coord_w2[l*64 + nt*16 + c16];
        }

        // hoisted edge-phase weights: issue global loads early, use after step A
        s8v w2f[8], wc1f[8];
#pragma unroll
        for (int nt = 0; nt < 4; ++nt)
#pragma unroll
            for (int kt = 0; kt < 2; ++kt) {
                w2f [nt*2+kt] = *(const s8v*)(wl +  8192 + ((nt*2+kt)*64 + lane)*8);
                wc1f[nt*2+kt] = *(const s8v*)(wl + 12288 + ((nt*2+kt)*64 + lane)*8);
            }
        union F4 { float4 v; float f[4]; };
        F4 W4[4];
        W4[0].v = *(const float4*)(w1row + q4*8);
        W4[1].v = *(const float4*)(w1row + q4*8 + 4);
        W4[2].v = *(const float4*)(w1row + 32 + q4*8);
        W4[3].v = *(const float4*)(w1row + 32 + q4*8 + 4);

        // ---- step A: wave w -> hs ntile w AND hd ntile w (shared A-frags) ----
        {
            s8v a[2][2];
#pragma unroll
            for (int mt = 0; mt < 2; ++mt)
#pragma unroll
                for (int kt = 0; kt < 2; ++kt)
                    a[mt][kt] = *(const s8v*)(s_habf + (mt*16 + c16)*136 + kt*32 + q4*8);
            v4f accS[2] = {{0.f,0.f,0.f,0.f},{0.f,0.f,0.f,0.f}};
            v4f accD[2] = {{0.f,0.f,0.f,0.f},{0.f,0.f,0.f,0.f}};
#pragma unroll
            for (int kt = 0; kt < 2; ++kt) {
                s8v bS = *(const s8v*)(wl + ((wave*2+kt)*64 + lane)*8);
                s8v bD = *(const s8v*)(wl + (((wave+4)*2+kt)*64 + lane)*8);
#pragma unroll
                for (int mt = 0; mt < 2; ++mt) {
                    accS[mt] = __builtin_amdgcn_mfma_f32_16x16x32_bf16(a[mt][kt], bS, accS[mt], 0, 0, 0);
                    accD[mt] = __builtin_amdgcn_mfma_f32_16x16x32_bf16(a[mt][kt], bD, accD[mt], 0, 0, 0);
                }
            }
            int col = wave*16 + c16;
            float tbv = s_tb4[l*64 + col];
#pragma unroll
            for (int mt = 0; mt < 2; ++mt)
#pragma unroll
                for (int reg = 0; reg < 4; ++reg) {
                    int row = mt*16 + q4*4 + reg;
                    s_hs[row*68 + col] = accS[mt][reg];
                    s_hd[row*68 + col] = accD[mt][reg] + tbv;
                }
        }
        __syncthreads();    // B2

        // ---- edge phase: wave owns 96 edges (dsts wave*8..+7), 6 tiles of 16 ----
        {
            unsigned short* tile = s_tiles16 + wave*1152;
            float* myshift = s_shift4 + wave*96;
            float miacc[4][2];   // rolling 2-slot window (slot = dst&1)
#pragma unroll
            for (int a2 = 0; a2 < 4; ++a2) { miacc[a2][0] = 0.f; miacc[a2][1] = 0.f; }

            auto flushd = [&](int d) {
                int s = d & 1;
#pragma unroll
                for (int nt = 0; nt < 4; ++nt) {
                    float v = miacc[nt][s];
                    v += __shfl_xor(v, 16);
                    v += __shfl_xor(v, 32);
                    s_habf[(wave*8 + d)*136 + 64 + nt*16 + c16] = f2bf(v);
                    miacc[nt][s] = 0.f;
                }
            };

            // all 6 tiles' edge meta upfront
            float2 me0 = s_emeta[wave*96 +  0 + c16];
            float2 me1 = s_emeta[wave*96 + 16 + c16];
            float2 me2 = s_emeta[wave*96 + 32 + c16];
            float2 me3 = s_emeta[wave*96 + 48 + c16];
            float2 me4 = s_emeta[wave*96 + 64 + c16];
            float2 me5 = s_emeta[wave*96 + 80 + c16];

            // preload tile 0 rows
            F4 H[4], G[4];
            {
                int srcn = __float_as_int(me0.y);
                int dstn = div12(wave*96 + c16);
                const float* hsr = s_hs + srcn*68 + q4*8;
                const float* hdr = s_hd + dstn*68 + q4*8;
                H[0].v = *(const float4*)(hsr);      H[1].v = *(const float4*)(hsr+4);
                H[2].v = *(const float4*)(hsr+32);   H[3].v = *(const float4*)(hsr+36);
                G[0].v = *(const float4*)(hdr);      G[1].v = *(const float4*)(hdr+4);
                G[2].v = *(const float4*)(hdr+32);   G[3].v = *(const float4*)(hdr+36);
            }

#pragma unroll
            for (int m = 0; m < 6; ++m) {
                const int e0g = wave*96 + m*16;
                const float dq = (m==0) ? me0.x : (m==1) ? me1.x : (m==2) ? me2.x
                               : (m==3) ? me3.x : (m==4) ? me4.x : me5.x;
                // build A-frags from preloaded H/G — packed-pair math
                union S8 { s8v v; unsigned u[4]; } A0, A1;
#pragma unroll
                for (int g2 = 0; g2 < 4; ++g2) {
                    v2f h0 = {H[g2].f[0], H[g2].f[1]}, h1 = {H[g2].f[2], H[g2].f[3]};
                    v2f g0 = {G[g2].f[0], G[g2].f[1]}, g1 = {G[g2].f[2], G[g2].f[3]};
                    v2f w0 = {W4[g2].f[0], W4[g2].f[1]}, w1 = {W4[g2].f[2], W4[g2].f[3]};
                    v2f t0 = h0 + g0 + w0 * dq;
                    v2f t1 = h1 + g1 + w1 * dq;
                    unsigned lo  = pk2bfu(silu2(t0));
                    unsigned hi2 = pk2bfu(silu2(t1));
                    if (g2 < 2) { A0.u[g2*2] = lo; A0.u[g2*2+1] = hi2; }
                    else        { A1.u[(g2-2)*2] = lo; A1.u[(g2-2)*2+1] = hi2; }
                }
                // prefetch tile m+1 rows (hides under m2/cw below)
                if (m < 5) {
                    float2 men = (m==0) ? me1 : (m==1) ? me2 : (m==2) ? me3
                               : (m==3) ? me4 : me5;
                    int srcn = __float_as_int(men.y);
                    int dstn = div12(e0g + 16 + c16);
                    const float* hsr = s_hs + srcn*68 + q4*8;
                    const float* hdr = s_hd + dstn*68 + q4*8;
                    H[0].v = *(const float4*)(hsr);      H[1].v = *(const float4*)(hsr+4);
                    H[2].v = *(const float4*)(hsr+32);   H[3].v = *(const float4*)(hsr+36);
                    G[0].v = *(const float4*)(hdr);      G[1].v = *(const float4*)(hdr+4);
                    G[2].v = *(const float4*)(hdr+32);   G[3].v = *(const float4*)(hdr+36);
                }

                // m2 = silu(m1@W2 + b2): cached w2f; mi into rolling slots
                const int dlo = (m < 3) ? m : m + 1;           // local dst ids {dlo, dlo+1}
                const int thr = 3 - (m % 3);                   // q4>=thr -> upper dst
                const int slo = dlo & 1;
#pragma unroll
                for (int nt = 0; nt < 4; ++nt) {
                    v4f acc = {0.f,0.f,0.f,0.f};
                    acc = __builtin_amdgcn_mfma_f32_16x16x32_bf16(A0.v, w2f[nt*2+0], acc, 0,0,0);
                    acc = __builtin_amdgcn_mfma_f32_16x16x32_bf16(A1.v, w2f[nt*2+1], acc, 0,0,0);
                    int col = nt*16 + c16;
                    v2f z01 = {acc[0] + b2e_v[nt], acc[1] + b2e_v[nt]};
                    v2f z23 = {acc[2] + b2e_v[nt], acc[3] + b2e_v[nt]};
                    v2f s01 = silu2(z01), s23 = silu2(z23);
                    unsigned p01 = pk2bfu(s01), p23 = pk2bfu(s23);
                    tile[(q4*4 + 0)*72 + col] = (unsigned short)p01;
                    tile[(q4*4 + 1)*72 + col] = (unsigned short)(p01 >> 16);
                    tile[(q4*4 + 2)*72 + col] = (unsigned short)p23;
                    tile[(q4*4 + 3)*72 + col] = (unsigned short)(p23 >> 16);
                    float msum = (s01.x + s01.y) + (s23.x + s23.y);
                    bool hi = (q4 >= thr);
                    miacc[nt][slo]     += hi ? 0.f : msum;
                    miacc[nt][slo ^ 1] += hi ? msum : 0.f;
                }
                asm volatile("s_waitcnt lgkmcnt(0)" ::: "memory");
                s8v c0 = *(const s8v*)(tile + c16*72 +      q4*8);
                s8v c1 = *(const s8v*)(tile + c16*72 + 32 + q4*8);
                // cw = silu(m2@Wc1 + cb1) . w2c — packed pairs (regs stay separate comps)
                v2f cwp01 = {0.f, 0.f}, cwp23 = {0.f, 0.f};
#pragma unroll
                for (int nt = 0; nt < 4; ++nt) {
                    v4f acc = {0.f,0.f,0.f,0.f};
                    acc = __builtin_amdgcn_mfma_f32_16x16x32_bf16(c0, wc1f[nt*2+0], acc, 0,0,0);
                    acc = __builtin_amdgcn_mfma_f32_16x16x32_bf16(c1, wc1f[nt*2+1], acc, 0,0,0);
                    v2f z01 = {acc[0] + cb1_v[nt], acc[1] + cb1_v[nt]};
                    v2f z23 = {acc[2] + cb1_v[nt], acc[3] + cb1_v[nt]};
                    cwp01 += silu2(z01) * w2c_v[nt];
                    cwp23 += silu2(z23) * w2c_v[nt];
                }
                float cwp[4] = {cwp01.x, cwp01.y, cwp23.x, cwp23.y};
#pragma unroll
                for (int reg = 0; reg < 4; ++reg) {
                    float v = cwp[reg];
                    v += __shfl_xor(v, 1); v += __shfl_xor(v, 2);
                    v += __shfl_xor(v, 4); v += __shfl_xor(v, 8);
                    int e = e0g + q4*4 + reg;
                    if (c16 < 3) {
                        int src = __float_as_int(s_emeta[e].y);
                        atomicAdd(&myshift[src*3 + c16], s_endc[e*3 + c16] * v);
                    }
                }
                // flush completed dsts (dst d complete iff (d+1)*12 <= m*16+16)
                if (m == 0) { flushd(0); }
                else if (m == 1) { flushd(1); }
                else if (m == 2) { flushd(2); flushd(3); }
                else if (m == 3) { flushd(4); }
                else if (m == 4) { flushd(5); }
                else             { flushd(6); flushd(7); }
            }
        }

        // prefetch GEMM1 B-frags BEFORE the barrier (2 nt-sets)
        const int mtA = wave & 1, nt0 = wave >> 1, nt1 = (wave >> 1) + 2;
        s8v bn1[8];
#pragma unroll
        for (int kt = 0; kt < 4; ++kt) {
            bn1[kt]   = *(const s8v*)(wl + 16384 + ((nt0*4+kt)*64 + lane)*8);
            bn1[4+kt] = *(const s8v*)(wl + 16384 + ((nt1*4+kt)*64 + lane)*8);
        }
        __syncthreads();    // B3

        // ---- node GEMM1: wave -> (mtA, nt0) and (mtA, nt1), shared A-frags ----
        {
            s8v aA[4];
#pragma unroll
            for (int kt = 0; kt < 4; ++kt)
                aA[kt] = *(const s8v*)(s_habf + (mtA*16 + c16)*136 + kt*32 + q4*8);
#pragma unroll
            for (int it = 0; it < 2; ++it) {
                int nt = it ? nt1 : nt0;
                int col = nt*16 + c16;
                float nbc = s_nb4[l*64 + col];
                v4f acc = {0.f,0.f,0.f,0.f};
#pragma unroll
                for (int kt = 0; kt < 4; ++kt)
                    acc = __builtin_amdgcn_mfma_f32_16x16x32_bf16(aA[kt], bn1[it*4+kt], acc, 0,0,0);
                v2f z01 = {acc[0] + nbc, acc[1] + nbc};
                v2f z23 = {acc[2] + nbc, acc[3] + nbc};
                unsigned p01 = pk2bfu(silu2(z01)), p23 = pk2bfu(silu2(z23));
                int r0 = mtA*16 + q4*4;
                s_n1bf[(r0+0)*72 + col] = (unsigned short)p01;
                s_n1bf[(r0+1)*72 + col] = (unsigned short)(p01 >> 16);
                s_n1bf[(r0+2)*72 + col] = (unsigned short)p23;
                s_n1bf[(r0+3)*72 + col] = (unsigned short)(p23 >> 16);
            }
        }
        // prefetch GEMM2 B-frags before B4
        s8v bn2[4];
        bn2[0] = *(const s8v*)(wl + 24576 + ((nt0*2+0)*64 + lane)*8);
        bn2[1] = *(const s8v*)(wl + 24576 + ((nt0*2+1)*64 + lane)*8);
        bn2[2] = *(const s8v*)(wl + 24576 + ((nt1*2+0)*64 + lane)*8);
        bn2[3] = *(const s8v*)(wl + 24576 + ((nt1*2+1)*64 + lane)*8);
        __syncthreads();    // B4

        // ---- node GEMM2: h += n1@Wn2 + b2, two nt sub-tiles, shared A-frags ----
        {
            s8v a0 = *(const s8v*)(s_n1bf + (mtA*16 + c16)*72 +      q4*8);
            s8v a1 = *(const s8v*)(s_n1bf + (mtA*16 + c16)*72 + 32 + q4*8);
#pragma unroll
            for (int it = 0; it < 2; ++it) {
                int nt = it ? nt1 : nt0;
                int col = nt*16 + c16;
                float nb2_v = node_b2[l*64 + col];
                v4f acc = {0.f,0.f,0.f,0.f};
                acc = __builtin_amdgcn_mfma_f32_16x16x32_bf16(a0, bn2[it*2+0], acc, 0,0,0);
                acc = __builtin_amdgcn_mfma_f32_16x16x32_bf16(a1, bn2[it*2+1], acc, 0,0,0);
#pragma unroll
                for (int reg = 0; reg < 4; ++reg) {
                    int row = mtA*16 + q4*4 + reg;
                    float hn = s_h[row*65 + col] + acc[reg] + nb2_v;
                    s_h[row*65 + col] = hn;
                    s_habf[row*136 + col] = f2bf(hn);
                }
            }
        }
        __syncthreads();    // B5
    }

    // ---------------- epilogue ----------------
    if (tid == 0) {
        float a=s_lat[0],b=s_lat[1],cc=s_lat[2];
        float d=s_lat[3],e=s_lat[4],f =s_lat[5];
        float g=s_lat[6],h2=s_lat[7],i2=s_lat[8];
        float A  =  (e*i2 - f*h2);
        float Bm = -(d*i2 - f*g);
        float C  =  (d*h2 - e*g);
        float det = a*A + b*Bm + cc*C;
        float rd = 1.0f/det;
        s_inv[0] = A*rd;
        s_inv[1] = -(b*i2 - cc*h2)*rd;
        s_inv[2] =  (b*f  - cc*e )*rd;
        s_inv[3] = Bm*rd;
        s_inv[4] =  (a*i2 - cc*g )*rd;
        s_inv[5] = -(a*f  - cc*d )*rd;
        s_inv[6] = C*rd;
        s_inv[7] = -(a*h2 - b*g  )*rd;
        s_inv[8] =  (a*e  - b*d  )*rd;
    }
    if (tid < 96) {
        s_shift[tid] = s_shift4[tid] + s_shift4[96 + tid]
                     + s_shift4[192 + tid] + s_shift4[288 + tid];
    }
    __syncthreads();
    if (tid < 96) {
        int r = tid/3, j = tid%3;
        float v = s_shift[r*3+0]*s_inv[0*3+j]
                + s_shift[r*3+1]*s_inv[1*3+j]
                + s_shift[r*3+2]*s_inv[2*3+j];
        out[(base + r)*3 + j] = v;
    }
    for (int q = tid; q < 2048; q += 256) {
        int row = q >> 6, colq = q & 63;
        out[NN*3 + base*64 + q] = s_h[row*65 + colq];
    }
}

extern "C" void kernel_launch(void* const* d_in, const int* in_sizes, int n_in,
                              void* d_out, int out_size, void* d_ws, size_t ws_size,
                              hipStream_t stream) {
    unsigned short* wbf = (unsigned short*)d_ws;
    prepack_w<<<(4*WPL/8 + 255)/256, 256, 0, stream>>>(
        (const float*)d_in[12], (const float*)d_in[14], (const float*)d_in[16],
        (const float*)d_in[19], (const float*)d_in[21], wbf);
    crystal_fused<<<NB, 256, 0, stream>>>(
        (const float*)d_in[0],  (const float*)d_in[1],  (const float*)d_in[2],  (const float*)d_in[3],
        (const float*)d_in[6],  (const float*)d_in[7],  (const float*)d_in[8],  (const float*)d_in[9],
        (const float*)d_in[10], (const float*)d_in[11],
        (const float*)d_in[12], (const float*)d_in[13], (const float*)d_in[15],
        (const float*)d_in[17], (const float*)d_in[18],
        (const float*)d_in[19], (const float*)d_in[20], (const float*)d_in[22],
        wbf, (float*)d_out);
}